// Round 11
// baseline (187.792 us; speedup 1.0000x reference)
//
#include <hip/hip_runtime.h>
#include <cstdint>

typedef short bf16x8 __attribute__((ext_vector_type(8)));
typedef float f32x4 __attribute__((ext_vector_type(4)));

#define MFMA16(a, b, c) __builtin_amdgcn_mfma_f32_16x16x32_bf16((a), (b), (c), 0, 0, 0)

// async global->LDS DMA, 16B per lane. LDS dest is wave-uniform base + lane*16.
__device__ __forceinline__ void gl16(const unsigned short* g, unsigned short* l) {
  __builtin_amdgcn_global_load_lds(
      (const __attribute__((address_space(1))) unsigned int*)g,
      (__attribute__((address_space(3))) unsigned int*)l, 16, 0, 0);
}

__device__ __forceinline__ unsigned short f2b(float f) {
  union { float f; unsigned int u; } x; x.f = f;
  unsigned int r = x.u + 0x7fffu + ((x.u >> 16) & 1u);
  return (unsigned short)(r >> 16);
}

// fast pack two fp32 -> packed bf16x2 (round half-up; fine for probs in [1,16])
__device__ __forceinline__ unsigned int pack2(float lo, float hi) {
  union { float f; unsigned int u; } a, b;
  a.f = lo; b.f = hi;
  return ((a.u + 0x8000u) >> 16) | ((b.u + 0x8000u) & 0xffff0000u);
}

#define NB 2
#define NS 2048
#define ND 768
#define NH 12
#define DHD 64
#define MTOK 4096  // NB*NS

// ws element offsets (ushort/bf16 elements)
#define OFF_XB 0
#define OFF_WB 3145728   // 5 x 589824 converted weights
#define OFF_QK 6094848   // 4 x 3145728 : Qr,Qi,Kr,Ki  [4096][768]
#define OFF_VT 18677760  // Vt [2][12][64][2048]

__global__ void cvt_kernel(const float* __restrict__ src,
                           unsigned short* __restrict__ dst, int n4, float scale) {
  int i = blockIdx.x * blockDim.x + threadIdx.x;
  if (i >= n4) return;
  float4 v = ((const float4*)src)[i];
  ushort4 o;
  o.x = f2b(v.x * scale); o.y = f2b(v.y * scale);
  o.z = f2b(v.z * scale); o.w = f2b(v.w * scale);
  ((ushort4*)dst)[i] = o;
}

// all 5 weight matrices in one launch
__global__ void wcvt_kernel(const float* __restrict__ s0, const float* __restrict__ s1,
                            const float* __restrict__ s2, const float* __restrict__ s3,
                            const float* __restrict__ s4, unsigned short* __restrict__ dst,
                            float qs) {
  const int bz = blockIdx.x / 576;           // 576 blocks per weight (147456/256)
  const int i = (blockIdx.x % 576) * 256 + threadIdx.x;
  const float* src = bz == 0 ? s0 : bz == 1 ? s1 : bz == 2 ? s2 : bz == 3 ? s3 : s4;
  const float scale = bz < 2 ? qs : 1.0f;    // Wqr, Wqi carry the exp2-domain scale
  float4 v = ((const float4*)src)[i];
  ushort4 o;
  o.x = f2b(v.x * scale); o.y = f2b(v.y * scale);
  o.z = f2b(v.z * scale); o.w = f2b(v.w * scale);
  ((ushort4*)(dst + bz * 589824))[i] = o;
}

// out = X @ W^T for 5 weights (z). z<4 -> row-major bf16 [4096][768];
// z==4 -> V transposed per head: Vt[b][h][dh][s].
//
// 256x256 tile, BK=64, 512 threads / 8 waves, double-buffered with
// COUNTED vmcnt (T4): the main loop NEVER drains vmcnt to 0. Per step:
//   s_waitcnt vmcnt(8); s_barrier   // prev step's 8 loads landed, block-wide
//   compute buf[kk&1]
//   s_barrier                       // all waves done reading buf[kk&1]
//   issue 8 loads for step kk+2 -> buf[kk&1]
// Loads get a full K-step of flight instead of being drained at each
// barrier (rounds 3-10 all had the vmcnt(0)-in-__syncthreads poison; m233:
// that drain is ~72% of a 2-phase step). Raw barriers are bracketed with
// asm memory clobbers so ds_reads / DMA issues can't migrate across.
// Final step peeled with vmcnt(0). Swizzle/epilogue identical to round 10.
__global__ __launch_bounds__(512) void proj_kernel(
    const unsigned short* __restrict__ Xb, const unsigned short* __restrict__ Wb,
    unsigned short* __restrict__ QK, unsigned short* __restrict__ Vt) {
  __shared__ __align__(16) unsigned short S[65536];  // 128 KB
  // A buffers: S[0], S[16384]; B buffers: S[32768], S[49152] (ushort offsets)

  const int lin = blockIdx.x;
  const int sb = (lin & 7) * 30 + (lin >> 3);  // XCD-chunked, 240 = 8*30
  const int z = sb / 48;
  const int rem = sb % 48;
  const int m0 = (rem / 3) * 256;
  const int n0 = (rem % 3) * 256;

  const unsigned short* Wz = Wb + z * 589824;
  const int tid = threadIdx.x;
  const int lane = tid & 63;
  const int w = tid >> 6;                     // 8 waves
  const int wm = (w >> 2) * 128;              // 2 m-halves
  const int wn = (w & 3) * 64;                // 4 n-quarters
  const int col = lane & 15, quad = lane >> 4;
  const int c7 = col & 7;

  // staging: wave w covers rows {w*8+lr + i*64, i=0..3} of each 256x64 tile
  const int lr = lane >> 3;                   // row within 8-row group
  const int lc = (lane & 7) ^ (lr & 7);       // pre-swizzled source chunk
  const unsigned short* gX = Xb + (m0 + w * 8 + lr) * ND + lc * 8;
  const unsigned short* gW = Wz + (n0 + w * 8 + lr) * ND + lc * 8;
  const int stg = (w * 8) * 64;               // wave dest base within a buffer

  f32x4 acc[8][4] = {};

  // prologue: stage K-steps 0 and 1 (16 loads/wave in flight)
#pragma unroll
  for (int i = 0; i < 4; i++) {
    gl16(gX + i * (64 * ND), S + stg + i * 4096);
    gl16(gW + i * (64 * ND), S + 32768 + stg + i * 4096);
  }
#pragma unroll
  for (int i = 0; i < 4; i++) {
    gl16(gX + i * (64 * ND) + 64, S + 16384 + stg + i * 4096);
    gl16(gW + i * (64 * ND) + 64, S + 49152 + stg + i * 4096);
  }

  for (int kk = 0; kk < 11; kk++) {
    // top: prev step's loads (for buf[kk&1]) landed; kk+1's may still fly
    asm volatile("s_waitcnt vmcnt(8)" ::: "memory");
    __builtin_amdgcn_s_barrier();
    asm volatile("" ::: "memory");

    const unsigned short* Ac = S + (kk & 1) * 16384;
    const unsigned short* Bc = S + 32768 + (kk & 1) * 16384;
#pragma unroll
    for (int ks = 0; ks < 2; ks++) {
      const int fo = (((ks * 4 + quad) ^ c7) * 8);
      bf16x8 af[8], bw[4];
#pragma unroll
      for (int t = 0; t < 8; t++)
        af[t] = *(const bf16x8*)(Ac + (wm + t * 16 + col) * 64 + fo);
#pragma unroll
      for (int u = 0; u < 4; u++)
        bw[u] = *(const bf16x8*)(Bc + (wn + u * 16 + col) * 64 + fo);
#pragma unroll
      for (int mt = 0; mt < 8; mt++)
#pragma unroll
        for (int nt = 0; nt < 4; nt++)
          acc[mt][nt] = MFMA16(af[mt], bw[nt], acc[mt][nt]);
    }

    // all waves done reading buf[kk&1]; only now may its overwrite be issued
    asm volatile("" ::: "memory");
    __builtin_amdgcn_s_barrier();
    asm volatile("" ::: "memory");

    if (kk < 10) {  // issue step kk+2 into buf[kk&1]
      const int k0n = (kk + 2) * 64;
      unsigned short* dA = S + (kk & 1) * 16384 + stg;
      unsigned short* dB = S + 32768 + (kk & 1) * 16384 + stg;
#pragma unroll
      for (int i = 0; i < 4; i++) {
        gl16(gX + i * (64 * ND) + k0n, dA + i * 4096);
        gl16(gW + i * (64 * ND) + k0n, dB + i * 4096);
      }
    }
  }

  // peeled final step (kk=11, buf1): only here do we drain to 0
  asm volatile("s_waitcnt vmcnt(0)" ::: "memory");
  __builtin_amdgcn_s_barrier();
  asm volatile("" ::: "memory");
  {
    const unsigned short* Ac = S + 16384;
    const unsigned short* Bc = S + 49152;
#pragma unroll
    for (int ks = 0; ks < 2; ks++) {
      const int fo = (((ks * 4 + quad) ^ c7) * 8);
      bf16x8 af[8], bw[4];
#pragma unroll
      for (int t = 0; t < 8; t++)
        af[t] = *(const bf16x8*)(Ac + (wm + t * 16 + col) * 64 + fo);
#pragma unroll
      for (int u = 0; u < 4; u++)
        bw[u] = *(const bf16x8*)(Bc + (wn + u * 16 + col) * 64 + fo);
#pragma unroll
      for (int mt = 0; mt < 8; mt++)
#pragma unroll
        for (int nt = 0; nt < 4; nt++)
          acc[mt][nt] = MFMA16(af[mt], bw[nt], acc[mt][nt]);
    }
  }

  // ---- epilogue: LDS-staged coalesced writeout, T[128][264], two halves ----
  unsigned short* T = S;

  if (z < 4) {
    unsigned short* out = QK + z * (MTOK * ND);
    const int wrow = w >> 2;
#pragma unroll
    for (int half = 0; half < 2; half++) {
      __syncthreads();
      if (wrow == half) {
#pragma unroll
        for (int mt = 0; mt < 8; mt++) {
          int rl = mt * 16 + quad * 4;  // local row within half
#pragma unroll
          for (int nt = 0; nt < 4; nt++) {
            int cl = wn + nt * 16 + col;
#pragma unroll
            for (int r = 0; r < 4; r++) T[(rl + r) * 264 + cl] = f2b(acc[mt][nt][r]);
          }
        }
      }
      __syncthreads();
#pragma unroll
      for (int p = 0; p < 8; p++) {
        int ci = p * 512 + tid;
        int row = ci >> 5;
        int c8 = (ci & 31) * 8;
        uint4 v = *(const uint4*)(T + row * 264 + c8);
        *(uint4*)(out + (m0 + half * 128 + row) * ND + n0 + c8) = v;
      }
    }
  } else {
    // Vt transpose: T[dh_local][s_local]; halves over the 256 output cols
    const int b = m0 >> 11;
    const int s_base = m0 & 2047;
    const int wcolh = (w & 3) >> 1;
#pragma unroll
    for (int half = 0; half < 2; half++) {
      __syncthreads();
      if (wcolh == half) {
        int clb = wn - half * 128;  // 0 or 64 for writer waves
#pragma unroll
        for (int mt = 0; mt < 8; mt++) {
          int rl = wm + mt * 16 + quad * 4;  // token index 0..255 (mult of 4)
#pragma unroll
          for (int nt = 0; nt < 4; nt++) {
            int cl = clb + nt * 16 + col;    // dh-local within half
            ushort4 pk;
            pk.x = f2b(acc[mt][nt][0]);
            pk.y = f2b(acc[mt][nt][1]);
            pk.z = f2b(acc[mt][nt][2]);
            pk.w = f2b(acc[mt][nt][3]);
            *(ushort4*)(T + cl * 264 + rl) = pk;
          }
        }
      }
      __syncthreads();
#pragma unroll
      for (int p = 0; p < 8; p++) {
        int ci = p * 512 + tid;
        int dhl = ci >> 5;
        int s8 = (ci & 31) * 8;
        int c = n0 + half * 128 + dhl;
        int h = c >> 6, dh = c & 63;
        uint4 v = *(const uint4*)(T + dhl * 264 + s8);
        *(uint4*)(Vt + ((b * NH + h) * DHD + dh) * NS + s_base + s8) = v;
      }
    }
  }
}

// Flash attention, scores transposed (S^T = K Q^T), complex magnitude variant.
// ROUND-5/9 VERSION (best measured 92.7 us): V-only double-buffer, Ps in LDS,
// K/Ki staged at mid barrier (covered by PV), V(t+1) into alt buffer.
// Load scheduling proven ~invariant (r3/r5/r8 all ~95); this is the cheapest.
// XCD-chunked swizzle keeps K/V panels resident in one XCD's L2.
__global__ __launch_bounds__(256) void attn_kernel(
    const unsigned short* __restrict__ QK, const unsigned short* __restrict__ Vt,
    float* __restrict__ outp) {
  __shared__ __align__(16) unsigned short Krs[4096];
  __shared__ __align__(16) unsigned short Kis[4096];
  __shared__ __align__(16) unsigned short Vts[8192];  // [2][64][64] double-buffered
  __shared__ __align__(16) unsigned short Ps[4096];

  const int lin = blockIdx.x + 32 * (blockIdx.y + 12 * blockIdx.z);
  const int sb = (lin & 7) * 96 + (lin >> 3);
  const int qt = sb & 31;
  const int h = (sb >> 5) % 12;
  const int b = sb / 384;
  const int tid = threadIdx.x, lane = tid & 63, w = tid >> 6;
  const int col = lane & 15, quad = lane >> 4;
  const int c7 = col & 7;
  const int jb = quad ^ c7;
  const int f0 = jb * 8, f1 = (jb ^ 4) * 8;  // swizzled fragment offsets (ushorts)

  const unsigned short* Qr = QK;
  const unsigned short* Qi = QK + MTOK * ND;
  const unsigned short* Krp = QK + 2 * MTOK * ND;
  const unsigned short* Kip = QK + 3 * MTOK * ND;

  const int q_tok = b * NS + qt * 64 + w * 16 + col;
  const int qoff = q_tok * ND + h * DHD;

  // Q as B-fragments: B[k=d][n=q], lane holds 8 consecutive d at its q.
  bf16x8 qrf[2], qif[2], qrn[2];
#pragma unroll
  for (int kk = 0; kk < 2; kk++) {
    qrf[kk] = *(const bf16x8*)(Qr + qoff + kk * 32 + quad * 8);
    qif[kk] = *(const bf16x8*)(Qi + qoff + kk * 32 + quad * 8);
    qrn[kk] = qrf[kk] ^ (short)0x8000;  // -Qr (bf16 sign flip)
  }

  // staging: wave w stages rows [w*8, w*8+8) and [32+w*8, ...) of each array.
  const int lr = lane >> 3;
  const int lc = (lane & 7) ^ (lr & 7);
  const unsigned short* gKr = Krp + (b * NS + w * 8 + lr) * ND + h * DHD + lc * 8;
  const unsigned short* gKi = Kip + (b * NS + w * 8 + lr) * ND + h * DHD + lc * 8;
  const unsigned short* gV = Vt + (b * NH + h) * (DHD * NS) + (w * 8 + lr) * NS + lc * 8;
  const int st = (w * 8) * 64;  // wave-uniform LDS base offset within a buffer

  unsigned short* PsW = Ps + w * 1024;

  f32x4 o[4] = {};  // O^T tiles: rows d = dt*16+quad*4+r, col q
  float lrow = 0.f;

  // prologue: stage tile 0 (K/Ki single buffer; V into buf 0)
  gl16(gKr, Krs + st);
  gl16(gKr + 32 * ND, Krs + st + 2048);
  gl16(gKi, Kis + st);
  gl16(gKi + 32 * ND, Kis + st + 2048);
  gl16(gV, Vts + st);
  gl16(gV + 32 * NS, Vts + st + 2048);
  gKr += 64 * ND;
  gKi += 64 * ND;
  gV += 64;

  int vb = 0;
  for (int kt = 0; kt < 32; kt++) {
    __syncthreads();  // drains vmcnt(0): tile kt's K/Ki/V landed

    // ---- QK^T phase (reads Krs/Kis; writes P to LDS) ----
#pragma unroll
    for (int mt = 0; mt < 4; mt++) {
      f32x4 sr = {}, si = {};
      const int rowb = (mt * 16 + col) * 64;
      bf16x8 kr0 = *(const bf16x8*)(Krs + rowb + f0);
      bf16x8 ki0 = *(const bf16x8*)(Kis + rowb + f0);
      bf16x8 kr1 = *(const bf16x8*)(Krs + rowb + f1);
      bf16x8 ki1 = *(const bf16x8*)(Kis + rowb + f1);
      sr = MFMA16(kr0, qrf[0], sr);
      sr = MFMA16(ki0, qif[0], sr);
      si = MFMA16(kr0, qif[0], si);
      si = MFMA16(ki0, qrn[0], si);
      sr = MFMA16(kr1, qrf[1], sr);
      sr = MFMA16(ki1, qif[1], sr);
      si = MFMA16(kr1, qif[1], si);
      si = MFMA16(ki1, qrn[1], si);

      float e0, e1, e2, e3;
      {
        float m0f = __builtin_amdgcn_sqrtf(sr[0] * sr[0] + si[0] * si[0]);
        float m1f = __builtin_amdgcn_sqrtf(sr[1] * sr[1] + si[1] * si[1]);
        float m2f = __builtin_amdgcn_sqrtf(sr[2] * sr[2] + si[2] * si[2]);
        float m3f = __builtin_amdgcn_sqrtf(sr[3] * sr[3] + si[3] * si[3]);
        e0 = __builtin_amdgcn_exp2f(m0f);
        e1 = __builtin_amdgcn_exp2f(m1f);
        e2 = __builtin_amdgcn_exp2f(m2f);
        e3 = __builtin_amdgcn_exp2f(m3f);
      }
      lrow += (e0 + e1) + (e2 + e3);
      uint2 pk;
      pk.x = pack2(e0, e1);
      pk.y = pack2(e2, e3);
      *(uint2*)(PsW + col * 64 + (((mt * 2 + (quad >> 1)) ^ c7) * 8) + (quad & 1) * 4) = pk;
    }

    __syncthreads();  // all waves done reading Krs/Kis (K dead); lgkm drained -> Ps visible

    // ---- stage tile kt+1 NOW: latency hides under the PV phase below ----
    if (kt < 31) {
      const int nb = (vb ^ 1) * 4096;
      gl16(gKr, Krs + st);
      gl16(gKr + 32 * ND, Krs + st + 2048);
      gl16(gKi, Kis + st);
      gl16(gKi + 32 * ND, Kis + st + 2048);
      gl16(gV, Vts + nb + st);
      gl16(gV + 32 * NS, Vts + nb + st + 2048);
      gKr += 64 * ND;
      gKi += 64 * ND;
      gV += 64;
    }

    // ---- PV phase: O^T += V^T · P^T (reads Vts[vb], Ps) ----
    const unsigned short* Vc = Vts + vb * 4096;
    bf16x8 pb0 = *(const bf16x8*)(PsW + col * 64 + f0);
    bf16x8 pb1 = *(const bf16x8*)(PsW + col * 64 + f1);
#pragma unroll
    for (int dt = 0; dt < 4; dt++) {
      const int rowv = (dt * 16 + col) * 64;
      bf16x8 va0 = *(const bf16x8*)(Vc + rowv + f0);
      bf16x8 va1 = *(const bf16x8*)(Vc + rowv + f1);
      o[dt] = MFMA16(va0, pb0, o[dt]);
      o[dt] = MFMA16(va1, pb1, o[dt]);
    }
    vb ^= 1;
  }

  lrow += __shfl_xor(lrow, 16);
  lrow += __shfl_xor(lrow, 32);
  float inv_l = 1.0f / lrow;
  float* op = outp + (size_t)q_tok * ND + h * DHD;
#pragma unroll
  for (int dt = 0; dt < 4; dt++) {
    float4 v;
    v.x = o[dt][0] * inv_l;
    v.y = o[dt][1] * inv_l;
    v.z = o[dt][2] * inv_l;
    v.w = o[dt][3] * inv_l;
    *(float4*)(op + dt * 16 + quad * 4) = v;
  }
}

extern "C" void kernel_launch(void* const* d_in, const int* in_sizes, int n_in,
                              void* d_out, int out_size, void* d_ws, size_t ws_size,
                              hipStream_t stream) {
  const float* X = (const float*)d_in[0];
  unsigned short* ws = (unsigned short*)d_ws;
  unsigned short* Xb = ws + OFF_XB;
  unsigned short* Wb = ws + OFF_WB;
  unsigned short* QK = ws + OFF_QK;
  unsigned short* Vt = ws + OFF_VT;

  // scale = 1/sqrt(Dh) * log2(e), folded into Wq so scores come out in exp2 domain
  const float QSCALE = 0.125f * 1.44269504088896f;

  cvt_kernel<<<3072, 256, 0, stream>>>(X, Xb, 786432, 1.0f);
  wcvt_kernel<<<2880, 256, 0, stream>>>((const float*)d_in[1], (const float*)d_in[2],
                                        (const float*)d_in[3], (const float*)d_in[4],
                                        (const float*)d_in[5], Wb, QSCALE);

  proj_kernel<<<240, 512, 0, stream>>>(Xb, Wb, QK, Vt);
  attn_kernel<<<dim3(32, 12, 2), 256, 0, stream>>>(QK, Vt, (float*)d_out);
}

// Round 13
// 184.220 us; speedup vs baseline: 1.0194x; 1.0194x over previous
//
#include <hip/hip_runtime.h>
#include <cstdint>

typedef short bf16x8 __attribute__((ext_vector_type(8)));
typedef float f32x4 __attribute__((ext_vector_type(4)));

#define MFMA16(a, b, c) __builtin_amdgcn_mfma_f32_16x16x32_bf16((a), (b), (c), 0, 0, 0)

// async global->LDS DMA, 16B per lane. LDS dest is wave-uniform base + lane*16.
__device__ __forceinline__ void gl16(const unsigned short* g, unsigned short* l) {
  __builtin_amdgcn_global_load_lds(
      (const __attribute__((address_space(1))) unsigned int*)g,
      (__attribute__((address_space(3))) unsigned int*)l, 16, 0, 0);
}

__device__ __forceinline__ unsigned short f2b(float f) {
  union { float f; unsigned int u; } x; x.f = f;
  unsigned int r = x.u + 0x7fffu + ((x.u >> 16) & 1u);
  return (unsigned short)(r >> 16);
}

// fast pack two fp32 -> packed bf16x2 (round half-up; REQUIRED — r12 showed
// v_cvt_pk_bf16_f32 truncates (RTZ) and fails absmax by 6.7x)
__device__ __forceinline__ unsigned int pack2(float lo, float hi) {
  union { float f; unsigned int u; } a, b;
  a.f = lo; b.f = hi;
  return ((a.u + 0x8000u) >> 16) | ((b.u + 0x8000u) & 0xffff0000u);
}

#define NB 2
#define NS 2048
#define ND 768
#define NH 12
#define DHD 64
#define MTOK 4096  // NB*NS

// ws element offsets (ushort/bf16 elements)
#define OFF_XB 0
#define OFF_WB 3145728   // 5 x 589824 converted weights
#define OFF_QK 6094848   // 4 x 3145728 : Qr,Qi,Kr,Ki  [4096][768]
#define OFF_VT 18677760  // Vt [2][12][64][2048]

__global__ void cvt_kernel(const float* __restrict__ src,
                           unsigned short* __restrict__ dst, int n4, float scale) {
  int i = blockIdx.x * blockDim.x + threadIdx.x;
  if (i >= n4) return;
  float4 v = ((const float4*)src)[i];
  ushort4 o;
  o.x = f2b(v.x * scale); o.y = f2b(v.y * scale);
  o.z = f2b(v.z * scale); o.w = f2b(v.w * scale);
  ((ushort4*)dst)[i] = o;
}

// all 5 weight matrices in one launch
__global__ void wcvt_kernel(const float* __restrict__ s0, const float* __restrict__ s1,
                            const float* __restrict__ s2, const float* __restrict__ s3,
                            const float* __restrict__ s4, unsigned short* __restrict__ dst,
                            float qs) {
  const int bz = blockIdx.x / 576;           // 576 blocks per weight (147456/256)
  const int i = (blockIdx.x % 576) * 256 + threadIdx.x;
  const float* src = bz == 0 ? s0 : bz == 1 ? s1 : bz == 2 ? s2 : bz == 3 ? s3 : s4;
  const float scale = bz < 2 ? qs : 1.0f;    // Wqr, Wqi carry the exp2-domain scale
  float4 v = ((const float4*)src)[i];
  ushort4 o;
  o.x = f2b(v.x * scale); o.y = f2b(v.y * scale);
  o.z = f2b(v.z * scale); o.w = f2b(v.w * scale);
  ((ushort4*)(dst + bz * 589824))[i] = o;
}

// out = X @ W^T for 5 weights (z). z<4 -> row-major bf16 [4096][768];
// z==4 -> V transposed per head: Vt[b][h][dh][s].
// 256x256 tile, BK=64, 512 threads/8 waves, 2-phase dbuf (r10 structure).
//
// READER-GROUPED XCD decode (r13): the 15 concurrent readers (3n x 5z) of
// each X m-panel are placed on ONE XCD: XCD x <- m in {2x,2x+1}, all (z,n).
// Theory: proj is fabric-bound (86us = 184MB staged at ~3.3TB/s because the
// r10 decode scattered each panel's readers across XCDs -> every read missed
// L2). With readers co-located, X fabric 90->6MB, W 8x5.6=45MB; per-K-step
// slice WS = 17x32KB = 544KB << 4MB L2.
__global__ __launch_bounds__(512) void proj_kernel(
    const unsigned short* __restrict__ Xb, const unsigned short* __restrict__ Wb,
    unsigned short* __restrict__ QK, unsigned short* __restrict__ Vt) {
  __shared__ __align__(16) unsigned short S[65536];  // 128 KB
  // A buffers: S[0], S[16384]; B buffers: S[32768], S[49152] (ushort offsets)

  const int lin = blockIdx.x;
  const int sb = (lin & 7) * 30 + (lin >> 3);  // XCD (lin&7) gets 30 consecutive sb
  const int m0 = (sb / 15) * 256;              // XCD x -> m-panels {2x, 2x+1}
  const int zn = sb % 15;
  const int z = zn / 3;
  const int n0 = (zn % 3) * 256;

  const unsigned short* Wz = Wb + z * 589824;
  const int tid = threadIdx.x;
  const int lane = tid & 63;
  const int w = tid >> 6;                     // 8 waves
  const int wm = (w >> 2) * 128;              // 2 m-halves
  const int wn = (w & 3) * 64;                // 4 n-quarters
  const int col = lane & 15, quad = lane >> 4;
  const int c7 = col & 7;

  // staging: wave w covers rows {w*8+lr + i*64, i=0..3} of each 256x64 tile
  const int lr = lane >> 3;                   // row within 8-row group
  const int lc = (lane & 7) ^ (lr & 7);       // pre-swizzled source chunk
  const unsigned short* gX = Xb + (m0 + w * 8 + lr) * ND + lc * 8;
  const unsigned short* gW = Wz + (n0 + w * 8 + lr) * ND + lc * 8;
  const int stg = (w * 8) * 64;               // wave dest base within a buffer

  f32x4 acc[8][4] = {};

  // prologue: stage K-step 0 into buf 0
#pragma unroll
  for (int i = 0; i < 4; i++) {
    gl16(gX + i * (64 * ND), S + stg + i * 4096);
    gl16(gW + i * (64 * ND), S + 32768 + stg + i * 4096);
  }
  __syncthreads();  // drain: buf0 visible

  int cur = 0;
  for (int kk = 0; kk < 12; kk++) {
    if (kk < 11) {  // issue next-step loads BEFORE compute (hidden under MFMAs)
      const int k0n = (kk + 1) * 64;
      unsigned short* dA = S + ((cur ^ 1) * 16384) + stg;
      unsigned short* dB = S + 32768 + ((cur ^ 1) * 16384) + stg;
#pragma unroll
      for (int i = 0; i < 4; i++) {
        gl16(gX + i * (64 * ND) + k0n, dA + i * 4096);
        gl16(gW + i * (64 * ND) + k0n, dB + i * 4096);
      }
    }
    const unsigned short* Ac = S + cur * 16384;
    const unsigned short* Bc = S + 32768 + cur * 16384;
#pragma unroll
    for (int ks = 0; ks < 2; ks++) {
      const int fo = (((ks * 4 + quad) ^ c7) * 8);
      bf16x8 af[8], bw[4];
#pragma unroll
      for (int t = 0; t < 8; t++)
        af[t] = *(const bf16x8*)(Ac + (wm + t * 16 + col) * 64 + fo);
#pragma unroll
      for (int u = 0; u < 4; u++)
        bw[u] = *(const bf16x8*)(Bc + (wn + u * 16 + col) * 64 + fo);
#pragma unroll
      for (int mt = 0; mt < 8; mt++)
#pragma unroll
        for (int nt = 0; nt < 4; nt++)
          acc[mt][nt] = MFMA16(af[mt], bw[nt], acc[mt][nt]);
    }
    __syncthreads();  // drains vmcnt(0): next buf ready; cur safe to overwrite
    cur ^= 1;
  }

  // ---- epilogue: LDS-staged coalesced writeout, T[128][264], two halves ----
  unsigned short* T = S;

  if (z < 4) {
    unsigned short* out = QK + z * (MTOK * ND);
    const int wrow = w >> 2;
#pragma unroll
    for (int half = 0; half < 2; half++) {
      __syncthreads();
      if (wrow == half) {
#pragma unroll
        for (int mt = 0; mt < 8; mt++) {
          int rl = mt * 16 + quad * 4;  // local row within half
#pragma unroll
          for (int nt = 0; nt < 4; nt++) {
            int cl = wn + nt * 16 + col;
#pragma unroll
            for (int r = 0; r < 4; r++) T[(rl + r) * 264 + cl] = f2b(acc[mt][nt][r]);
          }
        }
      }
      __syncthreads();
#pragma unroll
      for (int p = 0; p < 8; p++) {
        int ci = p * 512 + tid;
        int row = ci >> 5;
        int c8 = (ci & 31) * 8;
        uint4 v = *(const uint4*)(T + row * 264 + c8);
        *(uint4*)(out + (m0 + half * 128 + row) * ND + n0 + c8) = v;
      }
    }
  } else {
    // Vt transpose: T[dh_local][s_local]; halves over the 256 output cols
    const int b = m0 >> 11;
    const int s_base = m0 & 2047;
    const int wcolh = (w & 3) >> 1;
#pragma unroll
    for (int half = 0; half < 2; half++) {
      __syncthreads();
      if (wcolh == half) {
        int clb = wn - half * 128;  // 0 or 64 for writer waves
#pragma unroll
        for (int mt = 0; mt < 8; mt++) {
          int rl = wm + mt * 16 + quad * 4;  // token index 0..255 (mult of 4)
#pragma unroll
          for (int nt = 0; nt < 4; nt++) {
            int cl = clb + nt * 16 + col;    // dh-local within half
            ushort4 pk;
            pk.x = f2b(acc[mt][nt][0]);
            pk.y = f2b(acc[mt][nt][1]);
            pk.z = f2b(acc[mt][nt][2]);
            pk.w = f2b(acc[mt][nt][3]);
            *(ushort4*)(T + cl * 264 + rl) = pk;
          }
        }
      }
      __syncthreads();
#pragma unroll
      for (int p = 0; p < 8; p++) {
        int ci = p * 512 + tid;
        int dhl = ci >> 5;
        int s8 = (ci & 31) * 8;
        int c = n0 + half * 128 + dhl;
        int h = c >> 6, dh = c & 63;
        uint4 v = *(const uint4*)(T + dhl * 264 + s8);
        *(uint4*)(Vt + ((b * NH + h) * DHD + dh) * NS + s_base + s8) = v;
      }
    }
  }
}

// Flash attention, scores transposed (S^T = K Q^T), complex magnitude variant.
// ROUND-10 VERSION (best passing, 93.3 us): V-only double-buffer, Ps in LDS,
// K/Ki staged at mid barrier (covered by PV), V(t+1) into alt buffer, pack2.
// XCD-chunked swizzle keeps K/V panels resident in one XCD's L2.
__global__ __launch_bounds__(256) void attn_kernel(
    const unsigned short* __restrict__ QK, const unsigned short* __restrict__ Vt,
    float* __restrict__ outp) {
  __shared__ __align__(16) unsigned short Krs[4096];
  __shared__ __align__(16) unsigned short Kis[4096];
  __shared__ __align__(16) unsigned short Vts[8192];  // [2][64][64] double-buffered
  __shared__ __align__(16) unsigned short Ps[4096];

  const int lin = blockIdx.x + 32 * (blockIdx.y + 12 * blockIdx.z);
  const int sb = (lin & 7) * 96 + (lin >> 3);
  const int qt = sb & 31;
  const int h = (sb >> 5) % 12;
  const int b = sb / 384;
  const int tid = threadIdx.x, lane = tid & 63, w = tid >> 6;
  const int col = lane & 15, quad = lane >> 4;
  const int c7 = col & 7;
  const int jb = quad ^ c7;
  const int f0 = jb * 8, f1 = (jb ^ 4) * 8;  // swizzled fragment offsets (ushorts)

  const unsigned short* Qr = QK;
  const unsigned short* Qi = QK + MTOK * ND;
  const unsigned short* Krp = QK + 2 * MTOK * ND;
  const unsigned short* Kip = QK + 3 * MTOK * ND;

  const int q_tok = b * NS + qt * 64 + w * 16 + col;
  const int qoff = q_tok * ND + h * DHD;

  // Q as B-fragments: B[k=d][n=q], lane holds 8 consecutive d at its q.
  bf16x8 qrf[2], qif[2], qrn[2];
#pragma unroll
  for (int kk = 0; kk < 2; kk++) {
    qrf[kk] = *(const bf16x8*)(Qr + qoff + kk * 32 + quad * 8);
    qif[kk] = *(const bf16x8*)(Qi + qoff + kk * 32 + quad * 8);
    qrn[kk] = qrf[kk] ^ (short)0x8000;  // -Qr (bf16 sign flip)
  }

  // staging: wave w stages rows [w*8, w*8+8) and [32+w*8, ...) of each array.
  const int lr = lane >> 3;
  const int lc = (lane & 7) ^ (lr & 7);
  const unsigned short* gKr = Krp + (b * NS + w * 8 + lr) * ND + h * DHD + lc * 8;
  const unsigned short* gKi = Kip + (b * NS + w * 8 + lr) * ND + h * DHD + lc * 8;
  const unsigned short* gV = Vt + (b * NH + h) * (DHD * NS) + (w * 8 + lr) * NS + lc * 8;
  const int st = (w * 8) * 64;  // wave-uniform LDS base offset within a buffer

  unsigned short* PsW = Ps + w * 1024;

  f32x4 o[4] = {};  // O^T tiles: rows d = dt*16+quad*4+r, col q
  float lrow = 0.f;

  // prologue: stage tile 0 (K/Ki single buffer; V into buf 0)
  gl16(gKr, Krs + st);
  gl16(gKr + 32 * ND, Krs + st + 2048);
  gl16(gKi, Kis + st);
  gl16(gKi + 32 * ND, Kis + st + 2048);
  gl16(gV, Vts + st);
  gl16(gV + 32 * NS, Vts + st + 2048);
  gKr += 64 * ND;
  gKi += 64 * ND;
  gV += 64;

  int vb = 0;
  for (int kt = 0; kt < 32; kt++) {
    __syncthreads();  // drains vmcnt(0): tile kt's K/Ki/V landed

    // ---- QK^T phase (reads Krs/Kis; writes P to LDS) ----
#pragma unroll
    for (int mt = 0; mt < 4; mt++) {
      f32x4 sr = {}, si = {};
      const int rowb = (mt * 16 + col) * 64;
      bf16x8 kr0 = *(const bf16x8*)(Krs + rowb + f0);
      bf16x8 ki0 = *(const bf16x8*)(Kis + rowb + f0);
      bf16x8 kr1 = *(const bf16x8*)(Krs + rowb + f1);
      bf16x8 ki1 = *(const bf16x8*)(Kis + rowb + f1);
      sr = MFMA16(kr0, qrf[0], sr);
      sr = MFMA16(ki0, qif[0], sr);
      si = MFMA16(kr0, qif[0], si);
      si = MFMA16(ki0, qrn[0], si);
      sr = MFMA16(kr1, qrf[1], sr);
      sr = MFMA16(ki1, qif[1], sr);
      si = MFMA16(kr1, qif[1], si);
      si = MFMA16(ki1, qrn[1], si);

      float e0, e1, e2, e3;
      {
        float m0f = __builtin_amdgcn_sqrtf(sr[0] * sr[0] + si[0] * si[0]);
        float m1f = __builtin_amdgcn_sqrtf(sr[1] * sr[1] + si[1] * si[1]);
        float m2f = __builtin_amdgcn_sqrtf(sr[2] * sr[2] + si[2] * si[2]);
        float m3f = __builtin_amdgcn_sqrtf(sr[3] * sr[3] + si[3] * si[3]);
        e0 = __builtin_amdgcn_exp2f(m0f);
        e1 = __builtin_amdgcn_exp2f(m1f);
        e2 = __builtin_amdgcn_exp2f(m2f);
        e3 = __builtin_amdgcn_exp2f(m3f);
      }
      lrow += (e0 + e1) + (e2 + e3);
      uint2 pk;
      pk.x = pack2(e0, e1);
      pk.y = pack2(e2, e3);
      *(uint2*)(PsW + col * 64 + (((mt * 2 + (quad >> 1)) ^ c7) * 8) + (quad & 1) * 4) = pk;
    }

    __syncthreads();  // all waves done reading Krs/Kis (K dead); lgkm drained -> Ps visible

    // ---- stage tile kt+1 NOW: latency hides under the PV phase below ----
    if (kt < 31) {
      const int nb = (vb ^ 1) * 4096;
      gl16(gKr, Krs + st);
      gl16(gKr + 32 * ND, Krs + st + 2048);
      gl16(gKi, Kis + st);
      gl16(gKi + 32 * ND, Kis + st + 2048);
      gl16(gV, Vts + nb + st);
      gl16(gV + 32 * NS, Vts + nb + st + 2048);
      gKr += 64 * ND;
      gKi += 64 * ND;
      gV += 64;
    }

    // ---- PV phase: O^T += V^T · P^T (reads Vts[vb], Ps) ----
    const unsigned short* Vc = Vts + vb * 4096;
    bf16x8 pb0 = *(const bf16x8*)(PsW + col * 64 + f0);
    bf16x8 pb1 = *(const bf16x8*)(PsW + col * 64 + f1);
#pragma unroll
    for (int dt = 0; dt < 4; dt++) {
      const int rowv = (dt * 16 + col) * 64;
      bf16x8 va0 = *(const bf16x8*)(Vc + rowv + f0);
      bf16x8 va1 = *(const bf16x8*)(Vc + rowv + f1);
      o[dt] = MFMA16(va0, pb0, o[dt]);
      o[dt] = MFMA16(va1, pb1, o[dt]);
    }
    vb ^= 1;
  }

  lrow += __shfl_xor(lrow, 16);
  lrow += __shfl_xor(lrow, 32);
  float inv_l = 1.0f / lrow;
  float* op = outp + (size_t)q_tok * ND + h * DHD;
#pragma unroll
  for (int dt = 0; dt < 4; dt++) {
    float4 v;
    v.x = o[dt][0] * inv_l;
    v.y = o[dt][1] * inv_l;
    v.z = o[dt][2] * inv_l;
    v.w = o[dt][3] * inv_l;
    *(float4*)(op + dt * 16 + quad * 4) = v;
  }
}

extern "C" void kernel_launch(void* const* d_in, const int* in_sizes, int n_in,
                              void* d_out, int out_size, void* d_ws, size_t ws_size,
                              hipStream_t stream) {
  const float* X = (const float*)d_in[0];
  unsigned short* ws = (unsigned short*)d_ws;
  unsigned short* Xb = ws + OFF_XB;
  unsigned short* Wb = ws + OFF_WB;
  unsigned short* QK = ws + OFF_QK;
  unsigned short* Vt = ws + OFF_VT;

  // scale = 1/sqrt(Dh) * log2(e), folded into Wq so scores come out in exp2 domain
  const float QSCALE = 0.125f * 1.44269504088896f;

  cvt_kernel<<<3072, 256, 0, stream>>>(X, Xb, 786432, 1.0f);
  wcvt_kernel<<<2880, 256, 0, stream>>>((const float*)d_in[1], (const float*)d_in[2],
                                        (const float*)d_in[3], (const float*)d_in[4],
                                        (const float*)d_in[5], Wb, QSCALE);

  proj_kernel<<<240, 512, 0, stream>>>(Xb, Wb, QK, Vt);
  attn_kernel<<<dim3(32, 12, 2), 256, 0, stream>>>(QK, Vt, (float*)d_out);
}